// Round 2
// baseline (335.542 us; speedup 1.0000x reference)
//
#include <hip/hip_runtime.h>
#include <stdint.h>

#define NCOMP 5
#define DM 1024
#define LN_EPS 1e-5f

typedef __attribute__((ext_vector_type(8))) __bf16 bf16x8;
typedef __attribute__((ext_vector_type(4))) float f32x4;

__device__ __forceinline__ unsigned short f2bf(float f) {
    unsigned u = __builtin_bit_cast(unsigned, f);
    u += 0x7fffu + ((u >> 16) & 1u);   // round-to-nearest-even
    return (unsigned short)(u >> 16);
}

// -------- kernel 1: fused compartment LayerNorm + (W+I)->bf16 --------
// block = 128 threads, 4 units per block. unit < M: token LN; else: W row.
__global__ __launch_bounds__(128) void ln_w_kernel(
    const float* __restrict__ x, const int* __restrict__ cid,
    const float* __restrict__ gamma, const float* __restrict__ beta,
    const float* __restrict__ scale, const float* __restrict__ W,
    unsigned short* __restrict__ y, unsigned short* __restrict__ Wb, int M)
{
    const int tid = threadIdx.x;
    __shared__ float red[8];
    const int base = blockIdx.x * 4;
#pragma unroll
    for (int u = 0; u < 4; u++) {
        const int t = base + u;                 // block-uniform
        if (t < M) {
            const float* xp = x + (size_t)t * DM + tid * 8;
            const float4 a = *(const float4*)xp;
            const float4 b = *(const float4*)(xp + 4);
            float s  = a.x + a.y + a.z + a.w + b.x + b.y + b.z + b.w;
            float ss = a.x*a.x + a.y*a.y + a.z*a.z + a.w*a.w
                     + b.x*b.x + b.y*b.y + b.z*b.z + b.w*b.w;
#pragma unroll
            for (int off = 32; off > 0; off >>= 1) {
                s  += __shfl_down(s, off);
                ss += __shfl_down(ss, off);
            }
            float* rr = red + (u & 1) * 4;      // parity slot: no WAR hazard
            if ((tid & 63) == 0) { rr[tid >> 6] = s; rr[2 + (tid >> 6)] = ss; }
            __syncthreads();
            const float mu  = (rr[0] + rr[1]) * (1.0f / DM);
            const float var = (rr[2] + rr[3]) * (1.0f / DM) - mu * mu;
            const float rs  = rsqrtf(var + LN_EPS);
            const int craw  = cid[t];
            const bool valid = craw < NCOMP;    // reference guard
            const int c = min(max(craw, 0), NCOMP - 1);
            const float sc = scale[c];
            const float* gp = gamma + c * DM + tid * 8;
            const float* bp = beta  + c * DM + tid * 8;
            const float4 g0 = *(const float4*)gp;
            const float4 g1 = *(const float4*)(gp + 4);
            const float4 b0 = *(const float4*)bp;
            const float4 b1 = *(const float4*)(bp + 4);
            float o[8];
            o[0] = valid ? ((a.x - mu) * rs * g0.x + b0.x) * sc : a.x;
            o[1] = valid ? ((a.y - mu) * rs * g0.y + b0.y) * sc : a.y;
            o[2] = valid ? ((a.z - mu) * rs * g0.z + b0.z) * sc : a.z;
            o[3] = valid ? ((a.w - mu) * rs * g0.w + b0.w) * sc : a.w;
            o[4] = valid ? ((b.x - mu) * rs * g1.x + b1.x) * sc : b.x;
            o[5] = valid ? ((b.y - mu) * rs * g1.y + b1.y) * sc : b.y;
            o[6] = valid ? ((b.z - mu) * rs * g1.z + b1.z) * sc : b.z;
            o[7] = valid ? ((b.w - mu) * rs * g1.w + b1.w) * sc : b.w;
            uint4 p;
            p.x = (unsigned)f2bf(o[0]) | ((unsigned)f2bf(o[1]) << 16);
            p.y = (unsigned)f2bf(o[2]) | ((unsigned)f2bf(o[3]) << 16);
            p.z = (unsigned)f2bf(o[4]) | ((unsigned)f2bf(o[5]) << 16);
            p.w = (unsigned)f2bf(o[6]) | ((unsigned)f2bf(o[7]) << 16);
            *(uint4*)(y + (size_t)t * DM + tid * 8) = p;
        } else {
            const int row = t - M;              // 0..DM-1
            const float* wp = W + (size_t)row * DM + tid * 8;
            const float4 a = *(const float4*)wp;
            const float4 b = *(const float4*)(wp + 4);
            float o[8] = {a.x, a.y, a.z, a.w, b.x, b.y, b.z, b.w};
            const int d = row - tid * 8;        // fold identity: out = y*(W+I)^T + b
            if (d >= 0 && d < 8) o[d] += 1.0f;
            uint4 p;
            p.x = (unsigned)f2bf(o[0]) | ((unsigned)f2bf(o[1]) << 16);
            p.y = (unsigned)f2bf(o[2]) | ((unsigned)f2bf(o[3]) << 16);
            p.z = (unsigned)f2bf(o[4]) | ((unsigned)f2bf(o[5]) << 16);
            p.w = (unsigned)f2bf(o[6]) | ((unsigned)f2bf(o[7]) << 16);
            *(uint4*)(Wb + (size_t)row * DM + tid * 8) = p;
        }
    }
}

// -------- kernel 2: C = A * Bp^T + bias (Bp = W + I, bf16) --------
// 256x256 tile, BK=32, quad-buffered LDS (128 KiB), 8 waves (2Mx4N),
// per-wave output 128x64. Phase-pipelined: stage tile t+3 while computing
// tile t; counted vmcnt(8) once per K-tile (never 0 in steady state);
// raw s_barrier (NO __syncthreads -> no vmcnt(0) drain in the loop).
// MFMA operands SWAPPED (mfma(b,a)): lane holds C[m=..+fr][n=..+quad*4+r]
// -> 4 consecutive n per lane -> register-direct float4 C stores, zero
// LDS epilogue (the old ds_write_b32 transpose was ~4K LDS-pipe ops/CU).
__device__ __forceinline__ void gld16(const unsigned short* g, unsigned short* l) {
    __builtin_amdgcn_global_load_lds(
        (const __attribute__((address_space(1))) unsigned int*)(uintptr_t)g,
        (__attribute__((address_space(3))) unsigned int*)(uintptr_t)l,
        16, 0, 0);
}

__global__ __launch_bounds__(512, 2) void gemm_kernel(
    const unsigned short* __restrict__ A,
    const unsigned short* __restrict__ Bp,
    const float* __restrict__ bias,
    float* __restrict__ C, int M)
{
    constexpr int K = 1024, N = 1024;
    constexpr int BUF = 16384;                    // shorts per buffer: A 8192 + B 8192
    __shared__ __align__(16) unsigned short smem[4 * BUF];   // 128 KiB

    const int tid  = threadIdx.x;
    const int lane = tid & 63;
    const int wave = tid >> 6;
    const int wm   = (wave >> 2) * 128;           // 2 M-wave-groups
    const int wn   = (wave & 3) * 64;             // 4 N-wave-groups

    // T1: XCD-aware block swizzle (nwg = 512, divisible by 8 -> bijective)
    const int nwg = gridDim.x;
    int wg = blockIdx.x;
    if ((nwg & 7) == 0) wg = (wg & 7) * (nwg >> 3) + (wg >> 3);
    const int bm = (wg >> 2) * 256;               // n fastest -> A-panel L2 reuse
    const int bn = (wg & 3) * 256;

    // ---- staging addressing (T2: linear LDS dest + pre-swizzled global src) ----
    // physical chunk p holds logical chunk p ^ ((row>>1)&3); rows are 16-aligned
    // per wave-load so the XOR key reduces to lane bits.
    const int qsrc = (((lane & 3) ^ ((lane >> 3) & 3))) * 8;  // element offset
    const int rA0  = (wave * 2) * 16 + (lane >> 2);
    const unsigned short* gA0 = A  + (size_t)(bm + rA0) * K + qsrc;
    const unsigned short* gA1 = A  + (size_t)(bm + rA0 + 16) * K + qsrc;
    const unsigned short* gB0 = Bp + (size_t)(bn + rA0) * K + qsrc;
    const unsigned short* gB1 = Bp + (size_t)(bn + rA0 + 16) * K + qsrc;
    const int sA0 = (wave * 2) * 512 + lane * 8;  // shorts within buf (linear)
    const int sA1 = sA0 + 512;
    const int sB0 = 8192 + sA0;
    const int sB1 = 8192 + sA1;

    // ---- fragment read offset (swizzled): 2-way max bank aliasing = free ----
    const int fr   = lane & 15;
    const int quad = lane >> 4;
    const int loff = fr * 32 + ((quad ^ ((fr >> 1) & 3)) * 8);

    f32x4 acc[8][4] = {};

    // prologue: stage K-tiles 0,1,2 (3 tiles = 12 loads/thread in flight)
#pragma unroll
    for (int kt = 0; kt < 3; ++kt) {
        unsigned short* sb = smem + kt * BUF;
        gld16(gA0 + kt * 32, sb + sA0);
        gld16(gA1 + kt * 32, sb + sA1);
        gld16(gB0 + kt * 32, sb + sB0);
        gld16(gB1 + kt * 32, sb + sB1);
    }
    gA0 += 96; gA1 += 96; gB0 += 96; gB1 += 96;   // -> tile 3

    asm volatile("s_waitcnt vmcnt(8)" ::: "memory");  // tile 0 landed
    __builtin_amdgcn_s_barrier();

    for (int t = 0; t < 32; ++t) {
        const unsigned short* Asb = smem + (t & 3) * BUF;
        const unsigned short* Bsb = Asb + 8192;
        unsigned short* stg = smem + ((t + 3) & 3) * BUF;  // == buf of tile t-1
        const bool do_stage = (t < 29);

        // ---- phase A: mh=0 ----
        bf16x8 bfr[4], af[4];
#pragma unroll
        for (int j = 0; j < 4; ++j)
            bfr[j] = *(const bf16x8*)&Bsb[(wn + j * 16) * 32 + loff];
#pragma unroll
        for (int j = 0; j < 4; ++j)
            af[j] = *(const bf16x8*)&Asb[(wm + j * 16) * 32 + loff];
        if (do_stage) {                            // stage A-half of tile t+3
            gld16(gA0, stg + sA0);
            gld16(gA1, stg + sA1);
        }
        __builtin_amdgcn_s_barrier();
        asm volatile("s_waitcnt lgkmcnt(0)" ::: "memory");
        __builtin_amdgcn_s_setprio(1);
#pragma unroll
        for (int j = 0; j < 4; ++j)
#pragma unroll
            for (int n = 0; n < 4; ++n)
                acc[j][n] = __builtin_amdgcn_mfma_f32_16x16x32_bf16(
                    bfr[n], af[j], acc[j][n], 0, 0, 0);   // swapped: C^T fragment
        __builtin_amdgcn_s_setprio(0);
        __builtin_amdgcn_s_barrier();

        // ---- phase B: mh=1 (bfr reused from registers) ----
#pragma unroll
        for (int j = 0; j < 4; ++j)
            af[j] = *(const bf16x8*)&Asb[(wm + 64 + j * 16) * 32 + loff];
        if (do_stage) {                            // stage B-half of tile t+3
            gld16(gB0, stg + sB0);
            gld16(gB1, stg + sB1);
            gA0 += 32; gA1 += 32; gB0 += 32; gB1 += 32;
        }
        // once-per-K-tile counted wait: tile t+1 fully landed, tiles t+2,t+3
        // (8 loads) may stay in flight. Tail drains 8 -> 4 -> 0.
        if (t < 29)       asm volatile("s_waitcnt vmcnt(8)" ::: "memory");
        else if (t == 29) asm volatile("s_waitcnt vmcnt(4)" ::: "memory");
        else              asm volatile("s_waitcnt vmcnt(0)" ::: "memory");
        __builtin_amdgcn_s_barrier();
        asm volatile("s_waitcnt lgkmcnt(0)" ::: "memory");
        __builtin_amdgcn_s_setprio(1);
#pragma unroll
        for (int j = 0; j < 4; ++j)
#pragma unroll
            for (int n = 0; n < 4; ++n)
                acc[4 + j][n] = __builtin_amdgcn_mfma_f32_16x16x32_bf16(
                    bfr[n], af[j], acc[4 + j][n], 0, 0, 0);  // swapped
        __builtin_amdgcn_s_setprio(0);
        __builtin_amdgcn_s_barrier();
    }

    // ---- epilogue: register-direct stores, no LDS ----
    // Swapped-operand C/D layout: for acc[mi][ni], lane (quad,fr) reg r holds
    // C[bm+wm+mi*16+fr][bn+wn+ni*16+quad*4+r]. (mi 0..7 covers m-offsets
    // 0,16,..,112 since phase B wrote acc[4..7] at wm+64+j*16 = wm+(4+j)*16.)
    // Per store inst: 4 quads of each fr-row cover a contiguous 64B segment.
    const int q4 = quad * 4;
    float4 bv[4];
#pragma unroll
    for (int ni = 0; ni < 4; ++ni)
        bv[ni] = *(const float4*)&bias[bn + wn + ni * 16 + q4];
#pragma unroll
    for (int mi = 0; mi < 8; ++mi) {
        const size_t rowb = (size_t)(bm + wm + mi * 16 + fr) * N + bn + wn + q4;
#pragma unroll
        for (int ni = 0; ni < 4; ++ni) {
            float4 o;
            o.x = acc[mi][ni][0] + bv[ni].x;
            o.y = acc[mi][ni][1] + bv[ni].y;
            o.z = acc[mi][ni][2] + bv[ni].z;
            o.w = acc[mi][ni][3] + bv[ni].w;
            *(float4*)&C[rowb + ni * 16] = o;
        }
    }
}

extern "C" void kernel_launch(void* const* d_in, const int* in_sizes, int n_in,
                              void* d_out, int out_size, void* d_ws, size_t ws_size,
                              hipStream_t stream)
{
    const float* x     = (const float*)d_in[0];
    const int*   cid   = (const int*)d_in[1];
    const float* gamma = (const float*)d_in[2];
    const float* beta  = (const float*)d_in[3];
    const float* scale = (const float*)d_in[4];
    const float* W     = (const float*)d_in[5];
    const float* bias  = (const float*)d_in[6];
    float* out = (float*)d_out;

    const int M = in_sizes[0] / DM;                        // 32768 tokens
    unsigned short* yb = (unsigned short*)d_ws;            // M*1024 bf16 = 64 MB
    unsigned short* Wb = yb + (size_t)M * DM;              // 1024*1024 bf16 = 2 MB

    ln_w_kernel<<<(M + DM) / 4, 128, 0, stream>>>(x, cid, gamma, beta, scale, W, yb, Wb, M);
    gemm_kernel<<<dim3((M / 256) * 4), 512, 0, stream>>>(yb, Wb, bias, out, M);
}

// Round 3
// 321.802 us; speedup vs baseline: 1.0427x; 1.0427x over previous
//
#include <hip/hip_runtime.h>
#include <stdint.h>

#define NCOMP 5
#define DM 1024
#define LN_EPS 1e-5f

typedef __attribute__((ext_vector_type(8))) __bf16 bf16x8;
typedef __attribute__((ext_vector_type(4))) float f32x4;

__device__ __forceinline__ unsigned short f2bf(float f) {
    unsigned u = __builtin_bit_cast(unsigned, f);
    u += 0x7fffu + ((u >> 16) & 1u);   // round-to-nearest-even
    return (unsigned short)(u >> 16);
}

// -------- kernel 1: fused compartment LayerNorm + (W+I)->bf16 --------
__global__ __launch_bounds__(128) void ln_w_kernel(
    const float* __restrict__ x, const int* __restrict__ cid,
    const float* __restrict__ gamma, const float* __restrict__ beta,
    const float* __restrict__ scale, const float* __restrict__ W,
    unsigned short* __restrict__ y, unsigned short* __restrict__ Wb, int M)
{
    const int tid = threadIdx.x;
    __shared__ float red[8];
    const int base = blockIdx.x * 4;
#pragma unroll
    for (int u = 0; u < 4; u++) {
        const int t = base + u;                 // block-uniform
        if (t < M) {
            const float* xp = x + (size_t)t * DM + tid * 8;
            const float4 a = *(const float4*)xp;
            const float4 b = *(const float4*)(xp + 4);
            float s  = a.x + a.y + a.z + a.w + b.x + b.y + b.z + b.w;
            float ss = a.x*a.x + a.y*a.y + a.z*a.z + a.w*a.w
                     + b.x*b.x + b.y*b.y + b.z*b.z + b.w*b.w;
#pragma unroll
            for (int off = 32; off > 0; off >>= 1) {
                s  += __shfl_down(s, off);
                ss += __shfl_down(ss, off);
            }
            float* rr = red + (u & 1) * 4;      // parity slot: no WAR hazard
            if ((tid & 63) == 0) { rr[tid >> 6] = s; rr[2 + (tid >> 6)] = ss; }
            __syncthreads();
            const float mu  = (rr[0] + rr[1]) * (1.0f / DM);
            const float var = (rr[2] + rr[3]) * (1.0f / DM) - mu * mu;
            const float rs  = rsqrtf(var + LN_EPS);
            const int craw  = cid[t];
            const bool valid = craw < NCOMP;    // reference guard
            const int c = min(max(craw, 0), NCOMP - 1);
            const float sc = scale[c];
            const float* gp = gamma + c * DM + tid * 8;
            const float* bp = beta  + c * DM + tid * 8;
            const float4 g0 = *(const float4*)gp;
            const float4 g1 = *(const float4*)(gp + 4);
            const float4 b0 = *(const float4*)bp;
            const float4 b1 = *(const float4*)(bp + 4);
            float o[8];
            o[0] = valid ? ((a.x - mu) * rs * g0.x + b0.x) * sc : a.x;
            o[1] = valid ? ((a.y - mu) * rs * g0.y + b0.y) * sc : a.y;
            o[2] = valid ? ((a.z - mu) * rs * g0.z + b0.z) * sc : a.z;
            o[3] = valid ? ((a.w - mu) * rs * g0.w + b0.w) * sc : a.w;
            o[4] = valid ? ((b.x - mu) * rs * g1.x + b1.x) * sc : b.x;
            o[5] = valid ? ((b.y - mu) * rs * g1.y + b1.y) * sc : b.y;
            o[6] = valid ? ((b.z - mu) * rs * g1.z + b1.z) * sc : b.z;
            o[7] = valid ? ((b.w - mu) * rs * g1.w + b1.w) * sc : b.w;
            uint4 p;
            p.x = (unsigned)f2bf(o[0]) | ((unsigned)f2bf(o[1]) << 16);
            p.y = (unsigned)f2bf(o[2]) | ((unsigned)f2bf(o[3]) << 16);
            p.z = (unsigned)f2bf(o[4]) | ((unsigned)f2bf(o[5]) << 16);
            p.w = (unsigned)f2bf(o[6]) | ((unsigned)f2bf(o[7]) << 16);
            *(uint4*)(y + (size_t)t * DM + tid * 8) = p;
        } else {
            const int row = t - M;              // 0..DM-1
            const float* wp = W + (size_t)row * DM + tid * 8;
            const float4 a = *(const float4*)wp;
            const float4 b = *(const float4*)(wp + 4);
            float o[8] = {a.x, a.y, a.z, a.w, b.x, b.y, b.z, b.w};
            const int d = row - tid * 8;        // fold identity: out = y*(W+I)^T + b
            if (d >= 0 && d < 8) o[d] += 1.0f;
            uint4 p;
            p.x = (unsigned)f2bf(o[0]) | ((unsigned)f2bf(o[1]) << 16);
            p.y = (unsigned)f2bf(o[2]) | ((unsigned)f2bf(o[3]) << 16);
            p.z = (unsigned)f2bf(o[4]) | ((unsigned)f2bf(o[5]) << 16);
            p.w = (unsigned)f2bf(o[6]) | ((unsigned)f2bf(o[7]) << 16);
            *(uint4*)(Wb + (size_t)row * DM + tid * 8) = p;
        }
    }
}

// -------- kernel 2: C = A * Bp^T + bias (Bp = W + I, bf16) --------
// 256x256 tile, BK=32, quad-buffered LDS, 8 waves (2Mx4N), per-wave 128x64.
// FRAGMENT-PIPELINED: A/B fragments double-buffered in registers; next
// phase/tile ds_reads issue before the MFMA cluster that doesn't depend on
// them -> LDS pipe (reads of tile t+1) overlaps matrix pipe (tile t).
// ONE s_barrier per K-tile (was 4). Counted vmcnt(8) (12 loads in flight).
// Hazard ledger (bufs mod 4, windows = barrier..barrier): window reads bufs
// {t&3,(t+1)&3}, writes (t+3)&3 -> disjoint; old data of (t+3)&3 last read
// one barrier earlier; tile t+1 reads occur only after ALL waves' vmcnt +
// the barrier. gld_lds bumps vmcnt only; ds lgkm waits left to compiler.
__device__ __forceinline__ void gld16(const unsigned short* g, unsigned short* l) {
    __builtin_amdgcn_global_load_lds(
        (const __attribute__((address_space(1))) unsigned int*)(uintptr_t)g,
        (__attribute__((address_space(3))) unsigned int*)(uintptr_t)l,
        16, 0, 0);
}

#define GEMM_ITER(T, CA, CB, NA, NB)                                          \
  {                                                                           \
    const int t_ = (T);                                                       \
    const unsigned short* Asb = smem + (t_ & 3) * BUF;                        \
    /* afB reads (rows wm+64..127) from buf t; feeds phase-B MFMA */          \
    _Pragma("unroll")                                                         \
    for (int j = 0; j < 4; ++j)                                               \
        afB[j] = *(const bf16x8*)&Asb[(wm + 64 + j * 16) * 32 + loff];        \
    /* phase-A MFMA on fragments prefetched LAST iteration */                 \
    __builtin_amdgcn_s_setprio(1);                                            \
    _Pragma("unroll")                                                         \
    for (int j = 0; j < 4; ++j)                                               \
        _Pragma("unroll")                                                     \
        for (int n = 0; n < 4; ++n)                                           \
            acc[j][n] = __builtin_amdgcn_mfma_f32_16x16x32_bf16(              \
                CB[n], CA[j], acc[j][n], 0, 0, 0);                            \
    __builtin_amdgcn_s_setprio(0);                                            \
    /* stage tile t+3 (buf (t+3)&3 == (t-1)&3; its old data last read */      \
    /* before the PREVIOUS barrier) */                                        \
    if (t_ < 29) {                                                            \
        unsigned short* stg = smem + ((t_ + 3) & 3) * BUF;                    \
        const int kn = (t_ + 3) * 32;                                         \
        gld16(gA0 + kn, stg + sA0);                                           \
        gld16(gA1 + kn, stg + sA1);                                           \
        gld16(gB0 + kn, stg + sB0);                                           \
        gld16(gB1 + kn, stg + sB1);                                           \
    }                                                                         \
    /* counted wait: own tile-(t+1) loads landed; t+2,t+3 stay in flight */   \
    if (t_ < 29)       { asm volatile("s_waitcnt vmcnt(8)" ::: "memory"); }   \
    else if (t_ == 29) { asm volatile("s_waitcnt vmcnt(4)" ::: "memory"); }   \
    else               { asm volatile("s_waitcnt vmcnt(0)" ::: "memory"); }   \
    __builtin_amdgcn_s_barrier();   /* ALL waves' tile t+1 now in LDS */      \
    /* prefetch next-tile fragments; overlaps phase-B MFMA below */           \
    if (t_ < 31) {                                                            \
        const unsigned short* An = smem + ((t_ + 1) & 3) * BUF;               \
        const unsigned short* Bn = An + 8192;                                 \
        _Pragma("unroll")                                                     \
        for (int j = 0; j < 4; ++j)                                           \
            NB[j] = *(const bf16x8*)&Bn[(wn + j * 16) * 32 + loff];           \
        _Pragma("unroll")                                                     \
        for (int j = 0; j < 4; ++j)                                           \
            NA[j] = *(const bf16x8*)&An[(wm + j * 16) * 32 + loff];           \
    }                                                                         \
    /* phase-B MFMA (afB + CB, both already read) */                          \
    __builtin_amdgcn_s_setprio(1);                                            \
    _Pragma("unroll")                                                         \
    for (int j = 0; j < 4; ++j)                                               \
        _Pragma("unroll")                                                     \
        for (int n = 0; n < 4; ++n)                                           \
            acc[4 + j][n] = __builtin_amdgcn_mfma_f32_16x16x32_bf16(          \
                CB[n], afB[j], acc[4 + j][n], 0, 0, 0);                       \
    __builtin_amdgcn_s_setprio(0);                                            \
  }

__global__ __launch_bounds__(512, 2) void gemm_kernel(
    const unsigned short* __restrict__ A,
    const unsigned short* __restrict__ Bp,
    const float* __restrict__ bias,
    float* __restrict__ C, int M)
{
    constexpr int K = 1024, N = 1024;
    constexpr int BUF = 16384;                    // shorts per buffer: A 8192 + B 8192
    __shared__ __align__(16) unsigned short smem[4 * BUF];   // 128 KiB

    const int tid  = threadIdx.x;
    const int lane = tid & 63;
    const int wave = tid >> 6;
    const int wm   = (wave >> 2) * 128;           // 2 M-wave-groups
    const int wn   = (wave & 3) * 64;             // 4 N-wave-groups

    // T1: XCD-aware block swizzle (nwg = 512, divisible by 8 -> bijective)
    const int nwg = gridDim.x;
    int wg = blockIdx.x;
    if ((nwg & 7) == 0) wg = (wg & 7) * (nwg >> 3) + (wg >> 3);
    const int bm = (wg >> 2) * 256;               // n fastest -> A-panel L2 reuse
    const int bn = (wg & 3) * 256;

    // ---- staging addressing (T2: linear LDS dest + pre-swizzled global src) ----
    const int qsrc = (((lane & 3) ^ ((lane >> 3) & 3))) * 8;  // element offset
    const int rA0  = (wave * 2) * 16 + (lane >> 2);
    const unsigned short* gA0 = A  + (size_t)(bm + rA0) * K + qsrc;
    const unsigned short* gA1 = A  + (size_t)(bm + rA0 + 16) * K + qsrc;
    const unsigned short* gB0 = Bp + (size_t)(bn + rA0) * K + qsrc;
    const unsigned short* gB1 = Bp + (size_t)(bn + rA0 + 16) * K + qsrc;
    const int sA0 = (wave * 2) * 512 + lane * 8;  // shorts within buf (linear)
    const int sA1 = sA0 + 512;
    const int sB0 = 8192 + sA0;
    const int sB1 = 8192 + sA1;

    // ---- fragment read offset (swizzled): 2-way bank aliasing = free ----
    const int fr   = lane & 15;
    const int quad = lane >> 4;
    const int loff = fr * 32 + ((quad ^ ((fr >> 1) & 3)) * 8);

    f32x4 acc[8][4] = {};

    // prologue: stage K-tiles 0,1,2 (12 loads/thread in flight)
#pragma unroll
    for (int kt = 0; kt < 3; ++kt) {
        unsigned short* sb = smem + kt * BUF;
        gld16(gA0 + kt * 32, sb + sA0);
        gld16(gA1 + kt * 32, sb + sA1);
        gld16(gB0 + kt * 32, sb + sB0);
        gld16(gB1 + kt * 32, sb + sB1);
    }
    asm volatile("s_waitcnt vmcnt(8)" ::: "memory");  // own tile-0 loads landed
    __builtin_amdgcn_s_barrier();                     // all waves' tile 0 in LDS

    bf16x8 afA0[4], bfr0[4], afA1[4], bfr1[4], afB[4];
    {   // initial fragments (tile 0, phase A)
        const unsigned short* A0 = smem;
        const unsigned short* B0 = smem + 8192;
#pragma unroll
        for (int j = 0; j < 4; ++j)
            bfr0[j] = *(const bf16x8*)&B0[(wn + j * 16) * 32 + loff];
#pragma unroll
        for (int j = 0; j < 4; ++j)
            afA0[j] = *(const bf16x8*)&A0[(wm + j * 16) * 32 + loff];
    }

    for (int t = 0; t < 32; t += 2) {
        GEMM_ITER(t,     afA0, bfr0, afA1, bfr1)
        GEMM_ITER(t + 1, afA1, bfr1, afA0, bfr0)
    }

    // ---- epilogue: vectorized per-wave LDS transpose -> full 128B lines ----
    // Swapped-operand C/D layout: acc[mi][ni] reg r = C[wm+mi*16+fr][wn+ni*16+quad*4+r].
    // ds_write_b128 (2-way, free) -> ds_read_b128 (2-way) -> 256B/row stores.
    float* tb = (float*)smem + wave * 1088;   // 16 rows x 68 floats, per-wave private
    const int q4 = quad * 4;
    const float4 bvT = *(const float4*)&bias[bn + wn + fr * 4];
#pragma unroll
    for (int mi = 0; mi < 8; ++mi) {
#pragma unroll
        for (int ni = 0; ni < 4; ++ni)
            *(float4*)&tb[fr * 68 + ni * 16 + q4] = *(const float4*)&acc[mi][ni];
        // same-wave LDS: in-order pipe + compiler lgkmcnt waits; no barrier
#pragma unroll
        for (int j = 0; j < 4; ++j) {
            const int row = j * 4 + quad;
            const float4 v = *(const float4*)&tb[row * 68 + fr * 4];
            float4 o;
            o.x = v.x + bvT.x; o.y = v.y + bvT.y;
            o.z = v.z + bvT.z; o.w = v.w + bvT.w;
            *(float4*)&C[(size_t)(bm + wm + mi * 16 + row) * N + bn + wn + fr * 4] = o;
        }
    }
}

extern "C" void kernel_launch(void* const* d_in, const int* in_sizes, int n_in,
                              void* d_out, int out_size, void* d_ws, size_t ws_size,
                              hipStream_t stream)
{
    const float* x     = (const float*)d_in[0];
    const int*   cid   = (const int*)d_in[1];
    const float* gamma = (const float*)d_in[2];
    const float* beta  = (const float*)d_in[3];
    const float* scale = (const float*)d_in[4];
    const float* W     = (const float*)d_in[5];
    const float* bias  = (const float*)d_in[6];
    float* out = (float*)d_out;

    const int M = in_sizes[0] / DM;                        // 32768 tokens
    unsigned short* yb = (unsigned short*)d_ws;            // M*1024 bf16 = 64 MB
    unsigned short* Wb = yb + (size_t)M * DM;              // 1024*1024 bf16 = 2 MB

    ln_w_kernel<<<(M + DM) / 4, 128, 0, stream>>>(x, cid, gamma, beta, scale, W, yb, Wb, M);
    gemm_kernel<<<dim3((M / 256) * 4), 512, 0, stream>>>(yb, Wb, bias, out, M);
}

// Round 4
// 309.019 us; speedup vs baseline: 1.0858x; 1.0414x over previous
//
#include <hip/hip_runtime.h>
#include <stdint.h>

#define NCOMP 5
#define DM 1024
#define LN_EPS 1e-5f

typedef __attribute__((ext_vector_type(8))) __bf16 bf16x8;
typedef __attribute__((ext_vector_type(4))) float f32x4;

__device__ __forceinline__ unsigned short f2bf(float f) {
    unsigned u = __builtin_bit_cast(unsigned, f);
    u += 0x7fffu + ((u >> 16) & 1u);   // round-to-nearest-even
    return (unsigned short)(u >> 16);
}

// -------- kernel 1: fused compartment LayerNorm + (W+I)->bf16 --------
// ONE WAVE PER TOKEN: no LDS, no __syncthreads, reduction = 6 shfl_xor
// butterflies. 256-thread blocks = 4 independent waves = 4 units.
// Per-array access q in 0..3 is a fully contiguous segment per instruction
// (64 lanes x float4 = 1 KB loads, 64 x uint2 = 512 B stores).
__global__ __launch_bounds__(256) void ln_w_kernel(
    const float* __restrict__ x, const int* __restrict__ cid,
    const float* __restrict__ gamma, const float* __restrict__ beta,
    const float* __restrict__ scale, const float* __restrict__ W,
    unsigned short* __restrict__ y, unsigned short* __restrict__ Wb, int M)
{
    const int lane = threadIdx.x & 63;
    const int t = blockIdx.x * 4 + (threadIdx.x >> 6);   // wave-uniform unit id

    if (t < M) {
        const float* xp = x + (size_t)t * DM;
        float4 v[4];
#pragma unroll
        for (int q = 0; q < 4; ++q)
            v[q] = *(const float4*)(xp + q * 256 + lane * 4);

        float s = 0.f, ss = 0.f;
#pragma unroll
        for (int q = 0; q < 4; ++q) {
            s  += v[q].x + v[q].y + v[q].z + v[q].w;
            ss += v[q].x*v[q].x + v[q].y*v[q].y + v[q].z*v[q].z + v[q].w*v[q].w;
        }
#pragma unroll
        for (int off = 32; off; off >>= 1) {   // 64-lane butterfly, no LDS
            s  += __shfl_xor(s, off);
            ss += __shfl_xor(ss, off);
        }
        const float mu  = s * (1.0f / DM);
        const float var = ss * (1.0f / DM) - mu * mu;
        const float rs  = rsqrtf(var + LN_EPS);

        const int craw  = cid[t];
        const bool valid = craw < NCOMP;       // reference guard
        const int c = min(max(craw, 0), NCOMP - 1);
        const float sc = scale[c];
        const float* gp = gamma + (size_t)c * DM;
        const float* bp = beta  + (size_t)c * DM;
        unsigned short* yp = y + (size_t)t * DM;
#pragma unroll
        for (int q = 0; q < 4; ++q) {
            const int e = q * 256 + lane * 4;
            const float4 g  = *(const float4*)(gp + e);
            const float4 bb = *(const float4*)(bp + e);
            const float o0 = valid ? ((v[q].x - mu) * rs * g.x + bb.x) * sc : v[q].x;
            const float o1 = valid ? ((v[q].y - mu) * rs * g.y + bb.y) * sc : v[q].y;
            const float o2 = valid ? ((v[q].z - mu) * rs * g.z + bb.z) * sc : v[q].z;
            const float o3 = valid ? ((v[q].w - mu) * rs * g.w + bb.w) * sc : v[q].w;
            uint2 p;
            p.x = (unsigned)f2bf(o0) | ((unsigned)f2bf(o1) << 16);
            p.y = (unsigned)f2bf(o2) | ((unsigned)f2bf(o3) << 16);
            *(uint2*)(yp + e) = p;
        }
    } else if (t < M + DM) {
        const int row = t - M;                 // 0..DM-1
        const float* wp = W + (size_t)row * DM;
        unsigned short* wo = Wb + (size_t)row * DM;
#pragma unroll
        for (int q = 0; q < 4; ++q) {
            const int e = q * 256 + lane * 4;
            float4 a = *(const float4*)(wp + e);
            // fold identity: out = y*(W+I)^T + b
            a.x += (e + 0 == row) ? 1.0f : 0.0f;
            a.y += (e + 1 == row) ? 1.0f : 0.0f;
            a.z += (e + 2 == row) ? 1.0f : 0.0f;
            a.w += (e + 3 == row) ? 1.0f : 0.0f;
            uint2 p;
            p.x = (unsigned)f2bf(a.x) | ((unsigned)f2bf(a.y) << 16);
            p.y = (unsigned)f2bf(a.z) | ((unsigned)f2bf(a.w) << 16);
            *(uint2*)(wo + e) = p;
        }
    }
}

// -------- kernel 2: C = A * Bp^T + bias (Bp = W + I, bf16) --------
// 256x256 tile, BK=32, quad-buffered LDS, 8 waves (2Mx4N), per-wave 128x64.
// FRAGMENT-PIPELINED: A/B fragments double-buffered in registers; next
// phase/tile ds_reads issue before the MFMA cluster that doesn't depend on
// them -> LDS pipe (reads of tile t+1) overlaps matrix pipe (tile t).
// ONE s_barrier per K-tile. Counted vmcnt(8) (12 loads in flight).
// Hazard ledger (bufs mod 4, windows = barrier..barrier): window reads bufs
// {t&3,(t+1)&3}, writes (t+3)&3 -> disjoint; old data of (t+3)&3 last read
// one barrier earlier; tile t+1 reads occur only after ALL waves' vmcnt +
// the barrier. gld_lds bumps vmcnt only; ds lgkm waits left to compiler.
__device__ __forceinline__ void gld16(const unsigned short* g, unsigned short* l) {
    __builtin_amdgcn_global_load_lds(
        (const __attribute__((address_space(1))) unsigned int*)(uintptr_t)g,
        (__attribute__((address_space(3))) unsigned int*)(uintptr_t)l,
        16, 0, 0);
}

#define GEMM_ITER(T, CA, CB, NA, NB)                                          \
  {                                                                           \
    const int t_ = (T);                                                       \
    const unsigned short* Asb = smem + (t_ & 3) * BUF;                        \
    /* afB reads (rows wm+64..127) from buf t; feeds phase-B MFMA */          \
    _Pragma("unroll")                                                         \
    for (int j = 0; j < 4; ++j)                                               \
        afB[j] = *(const bf16x8*)&Asb[(wm + 64 + j * 16) * 32 + loff];        \
    /* phase-A MFMA on fragments prefetched LAST iteration */                 \
    __builtin_amdgcn_s_setprio(1);                                            \
    _Pragma("unroll")                                                         \
    for (int j = 0; j < 4; ++j)                                               \
        _Pragma("unroll")                                                     \
        for (int n = 0; n < 4; ++n)                                           \
            acc[j][n] = __builtin_amdgcn_mfma_f32_16x16x32_bf16(              \
                CB[n], CA[j], acc[j][n], 0, 0, 0);                            \
    __builtin_amdgcn_s_setprio(0);                                            \
    /* stage tile t+3 (buf (t+3)&3 == (t-1)&3; its old data last read */      \
    /* before the PREVIOUS barrier) */                                        \
    if (t_ < 29) {                                                            \
        unsigned short* stg = smem + ((t_ + 3) & 3) * BUF;                    \
        const int kn = (t_ + 3) * 32;                                         \
        gld16(gA0 + kn, stg + sA0);                                           \
        gld16(gA1 + kn, stg + sA1);                                           \
        gld16(gB0 + kn, stg + sB0);                                           \
        gld16(gB1 + kn, stg + sB1);                                           \
    }                                                                         \
    /* counted wait: own tile-(t+1) loads landed; t+2,t+3 stay in flight */   \
    if (t_ < 29)       { asm volatile("s_waitcnt vmcnt(8)" ::: "memory"); }   \
    else if (t_ == 29) { asm volatile("s_waitcnt vmcnt(4)" ::: "memory"); }   \
    else               { asm volatile("s_waitcnt vmcnt(0)" ::: "memory"); }   \
    __builtin_amdgcn_s_barrier();   /* ALL waves' tile t+1 now in LDS */      \
    /* prefetch next-tile fragments; overlaps phase-B MFMA below */           \
    if (t_ < 31) {                                                            \
        const unsigned short* An = smem + ((t_ + 1) & 3) * BUF;               \
        const unsigned short* Bn = An + 8192;                                 \
        _Pragma("unroll")                                                     \
        for (int j = 0; j < 4; ++j)                                           \
            NB[j] = *(const bf16x8*)&Bn[(wn + j * 16) * 32 + loff];           \
        _Pragma("unroll")                                                     \
        for (int j = 0; j < 4; ++j)                                           \
            NA[j] = *(const bf16x8*)&An[(wm + j * 16) * 32 + loff];           \
    }                                                                         \
    /* phase-B MFMA (afB + CB, both already read) */                          \
    __builtin_amdgcn_s_setprio(1);                                            \
    _Pragma("unroll")                                                         \
    for (int j = 0; j < 4; ++j)                                               \
        _Pragma("unroll")                                                     \
        for (int n = 0; n < 4; ++n)                                           \
            acc[4 + j][n] = __builtin_amdgcn_mfma_f32_16x16x32_bf16(          \
                CB[n], afB[j], acc[4 + j][n], 0, 0, 0);                       \
    __builtin_amdgcn_s_setprio(0);                                            \
  }

__global__ __launch_bounds__(512, 2) void gemm_kernel(
    const unsigned short* __restrict__ A,
    const unsigned short* __restrict__ Bp,
    const float* __restrict__ bias,
    float* __restrict__ C, int M)
{
    constexpr int K = 1024, N = 1024;
    constexpr int BUF = 16384;                    // shorts per buffer: A 8192 + B 8192
    __shared__ __align__(16) unsigned short smem[4 * BUF];   // 128 KiB

    const int tid  = threadIdx.x;
    const int lane = tid & 63;
    const int wave = tid >> 6;
    const int wm   = (wave >> 2) * 128;           // 2 M-wave-groups
    const int wn   = (wave & 3) * 64;             // 4 N-wave-groups

    // T1: XCD-aware block swizzle (nwg = 512, divisible by 8 -> bijective)
    const int nwg = gridDim.x;
    int wg = blockIdx.x;
    if ((nwg & 7) == 0) wg = (wg & 7) * (nwg >> 3) + (wg >> 3);
    const int bm = (wg >> 2) * 256;               // n fastest -> A-panel L2 reuse
    const int bn = (wg & 3) * 256;

    // ---- staging addressing (T2: linear LDS dest + pre-swizzled global src) ----
    const int qsrc = (((lane & 3) ^ ((lane >> 3) & 3))) * 8;  // element offset
    const int rA0  = (wave * 2) * 16 + (lane >> 2);
    const unsigned short* gA0 = A  + (size_t)(bm + rA0) * K + qsrc;
    const unsigned short* gA1 = A  + (size_t)(bm + rA0 + 16) * K + qsrc;
    const unsigned short* gB0 = Bp + (size_t)(bn + rA0) * K + qsrc;
    const unsigned short* gB1 = Bp + (size_t)(bn + rA0 + 16) * K + qsrc;
    const int sA0 = (wave * 2) * 512 + lane * 8;  // shorts within buf (linear)
    const int sA1 = sA0 + 512;
    const int sB0 = 8192 + sA0;
    const int sB1 = 8192 + sA1;

    // ---- fragment read offset (swizzled): 2-way bank aliasing = free ----
    const int fr   = lane & 15;
    const int quad = lane >> 4;
    const int loff = fr * 32 + ((quad ^ ((fr >> 1) & 3)) * 8);

    f32x4 acc[8][4] = {};

    // prologue: stage K-tiles 0,1,2 (12 loads/thread in flight)
#pragma unroll
    for (int kt = 0; kt < 3; ++kt) {
        unsigned short* sb = smem + kt * BUF;
        gld16(gA0 + kt * 32, sb + sA0);
        gld16(gA1 + kt * 32, sb + sA1);
        gld16(gB0 + kt * 32, sb + sB0);
        gld16(gB1 + kt * 32, sb + sB1);
    }
    asm volatile("s_waitcnt vmcnt(8)" ::: "memory");  // own tile-0 loads landed
    __builtin_amdgcn_s_barrier();                     // all waves' tile 0 in LDS

    bf16x8 afA0[4], bfr0[4], afA1[4], bfr1[4], afB[4];
    {   // initial fragments (tile 0, phase A)
        const unsigned short* A0 = smem;
        const unsigned short* B0 = smem + 8192;
#pragma unroll
        for (int j = 0; j < 4; ++j)
            bfr0[j] = *(const bf16x8*)&B0[(wn + j * 16) * 32 + loff];
#pragma unroll
        for (int j = 0; j < 4; ++j)
            afA0[j] = *(const bf16x8*)&A0[(wm + j * 16) * 32 + loff];
    }

    for (int t = 0; t < 32; t += 2) {
        GEMM_ITER(t,     afA0, bfr0, afA1, bfr1)
        GEMM_ITER(t + 1, afA1, bfr1, afA0, bfr0)
    }

    // ---- epilogue: vectorized per-wave LDS transpose -> full 128B lines ----
    // Swapped-operand C/D layout: acc[mi][ni] reg r = C[wm+mi*16+fr][wn+ni*16+quad*4+r].
    // ds_write_b128 (2-way, free) -> ds_read_b128 (2-way) -> 256B/row stores.
    float* tb = (float*)smem + wave * 1088;   // 16 rows x 68 floats, per-wave private
    const int q4 = quad * 4;
    const float4 bvT = *(const float4*)&bias[bn + wn + fr * 4];
#pragma unroll
    for (int mi = 0; mi < 8; ++mi) {
#pragma unroll
        for (int ni = 0; ni < 4; ++ni)
            *(float4*)&tb[fr * 68 + ni * 16 + q4] = *(const float4*)&acc[mi][ni];
        // same-wave LDS: in-order pipe + compiler lgkmcnt waits; no barrier
#pragma unroll
        for (int j = 0; j < 4; ++j) {
            const int row = j * 4 + quad;
            const float4 v = *(const float4*)&tb[row * 68 + fr * 4];
            float4 o;
            o.x = v.x + bvT.x; o.y = v.y + bvT.y;
            o.z = v.z + bvT.z; o.w = v.w + bvT.w;
            *(float4*)&C[(size_t)(bm + wm + mi * 16 + row) * N + bn + wn + fr * 4] = o;
        }
    }
}

extern "C" void kernel_launch(void* const* d_in, const int* in_sizes, int n_in,
                              void* d_out, int out_size, void* d_ws, size_t ws_size,
                              hipStream_t stream)
{
    const float* x     = (const float*)d_in[0];
    const int*   cid   = (const int*)d_in[1];
    const float* gamma = (const float*)d_in[2];
    const float* beta  = (const float*)d_in[3];
    const float* scale = (const float*)d_in[4];
    const float* W     = (const float*)d_in[5];
    const float* bias  = (const float*)d_in[6];
    float* out = (float*)d_out;

    const int M = in_sizes[0] / DM;                        // 32768 tokens
    unsigned short* yb = (unsigned short*)d_ws;            // M*1024 bf16 = 64 MB
    unsigned short* Wb = yb + (size_t)M * DM;              // 1024*1024 bf16 = 2 MB

    // one wave per unit: (M + DM) units, 4 waves per 256-thread block
    ln_w_kernel<<<(M + DM) / 4, 256, 0, stream>>>(x, cid, gamma, beta, scale, W, yb, Wb, M);
    gemm_kernel<<<dim3((M / 256) * 4), 512, 0, stream>>>(yb, Wb, bias, out, M);
}

// Round 5
// 307.393 us; speedup vs baseline: 1.0916x; 1.0053x over previous
//
#include <hip/hip_runtime.h>
#include <stdint.h>

#define NCOMP 5
#define DM 1024
#define LN_EPS 1e-5f

typedef __attribute__((ext_vector_type(8))) __bf16 bf16x8;
typedef __attribute__((ext_vector_type(4))) float f32x4;

__device__ __forceinline__ unsigned short f2bf(float f) {
    unsigned u = __builtin_bit_cast(unsigned, f);
    u += 0x7fffu + ((u >> 16) & 1u);   // round-to-nearest-even
    return (unsigned short)(u >> 16);
}

// -------- kernel 1: fused compartment LayerNorm + (W+I)->bf16 --------
// ONE WAVE PER TOKEN: no LDS, no __syncthreads, reduction = 6 shfl_xor
// butterflies. 256-thread blocks = 4 independent waves = 4 units.
__global__ __launch_bounds__(256) void ln_w_kernel(
    const float* __restrict__ x, const int* __restrict__ cid,
    const float* __restrict__ gamma, const float* __restrict__ beta,
    const float* __restrict__ scale, const float* __restrict__ W,
    unsigned short* __restrict__ y, unsigned short* __restrict__ Wb, int M)
{
    const int lane = threadIdx.x & 63;
    const int t = blockIdx.x * 4 + (threadIdx.x >> 6);   // wave-uniform unit id

    if (t < M) {
        const float* xp = x + (size_t)t * DM;
        float4 v[4];
#pragma unroll
        for (int q = 0; q < 4; ++q)
            v[q] = *(const float4*)(xp + q * 256 + lane * 4);

        float s = 0.f, ss = 0.f;
#pragma unroll
        for (int q = 0; q < 4; ++q) {
            s  += v[q].x + v[q].y + v[q].z + v[q].w;
            ss += v[q].x*v[q].x + v[q].y*v[q].y + v[q].z*v[q].z + v[q].w*v[q].w;
        }
#pragma unroll
        for (int off = 32; off; off >>= 1) {   // 64-lane butterfly, no LDS
            s  += __shfl_xor(s, off);
            ss += __shfl_xor(ss, off);
        }
        const float mu  = s * (1.0f / DM);
        const float var = ss * (1.0f / DM) - mu * mu;
        const float rs  = rsqrtf(var + LN_EPS);

        const int craw  = cid[t];
        const bool valid = craw < NCOMP;       // reference guard
        const int c = min(max(craw, 0), NCOMP - 1);
        const float sc = scale[c];
        const float* gp = gamma + (size_t)c * DM;
        const float* bp = beta  + (size_t)c * DM;
        unsigned short* yp = y + (size_t)t * DM;
#pragma unroll
        for (int q = 0; q < 4; ++q) {
            const int e = q * 256 + lane * 4;
            const float4 g  = *(const float4*)(gp + e);
            const float4 bb = *(const float4*)(bp + e);
            const float o0 = valid ? ((v[q].x - mu) * rs * g.x + bb.x) * sc : v[q].x;
            const float o1 = valid ? ((v[q].y - mu) * rs * g.y + bb.y) * sc : v[q].y;
            const float o2 = valid ? ((v[q].z - mu) * rs * g.z + bb.z) * sc : v[q].z;
            const float o3 = valid ? ((v[q].w - mu) * rs * g.w + bb.w) * sc : v[q].w;
            uint2 p;
            p.x = (unsigned)f2bf(o0) | ((unsigned)f2bf(o1) << 16);
            p.y = (unsigned)f2bf(o2) | ((unsigned)f2bf(o3) << 16);
            *(uint2*)(yp + e) = p;
        }
    } else if (t < M + DM) {
        const int row = t - M;                 // 0..DM-1
        const float* wp = W + (size_t)row * DM;
        unsigned short* wo = Wb + (size_t)row * DM;
#pragma unroll
        for (int q = 0; q < 4; ++q) {
            const int e = q * 256 + lane * 4;
            float4 a = *(const float4*)(wp + e);
            // fold identity: out = y*(W+I)^T + b
            a.x += (e + 0 == row) ? 1.0f : 0.0f;
            a.y += (e + 1 == row) ? 1.0f : 0.0f;
            a.z += (e + 2 == row) ? 1.0f : 0.0f;
            a.w += (e + 3 == row) ? 1.0f : 0.0f;
            uint2 p;
            p.x = (unsigned)f2bf(a.x) | ((unsigned)f2bf(a.y) << 16);
            p.y = (unsigned)f2bf(a.z) | ((unsigned)f2bf(a.w) << 16);
            *(uint2*)(wo + e) = p;
        }
    }
}

// -------- kernel 2: C = A * Bp^T + bias (Bp = W + I, bf16) --------
// 256x256 tile, BK=32, quad-buffered LDS, 8 waves (2Mx4N), per-wave 128x64.
// FULL register double-buffering: ALL 12 fragments (afA,afB,bfr) of tile
// t+1 are read inside tile t's MFMA shadows. Iteration: MFMA-A (current
// regs, zero lgkm dependency at issue) -> stage t+3 -> vmcnt(8) -> barrier
// -> read bfr'/afA' (8) -> MFMA-B (overlaps those reads) -> read afB' (4,
// hidden under next iter's MFMA-A). One s_barrier per K-tile.
// Hazard ledger (bufs mod 4): last read of buf X (tile u, in window after
// barrier_{u-1}) and overwrite-issue (tile u+4 staged after barrier_u) are
// separated by barrier_u -- same separation R3/R4 ran bit-stable with.
__device__ __forceinline__ void gld16(const unsigned short* g, unsigned short* l) {
    __builtin_amdgcn_global_load_lds(
        (const __attribute__((address_space(1))) unsigned int*)(uintptr_t)g,
        (__attribute__((address_space(3))) unsigned int*)(uintptr_t)l,
        16, 0, 0);
}

#define GEMM_ITER(T, CA, CAB, CB, NA, NAB, NB)                                \
  {                                                                           \
    const int t_ = (T);                                                       \
    /* MFMA-A: acc[0..3] on current regs (read during iter t-1) */            \
    __builtin_amdgcn_s_setprio(1);                                            \
    _Pragma("unroll")                                                         \
    for (int j = 0; j < 4; ++j)                                               \
        _Pragma("unroll")                                                     \
        for (int n = 0; n < 4; ++n)                                           \
            acc[j][n] = __builtin_amdgcn_mfma_f32_16x16x32_bf16(              \
                CB[n], CA[j], acc[j][n], 0, 0, 0);                            \
    __builtin_amdgcn_s_setprio(0);                                            \
    /* stage tile t+3 (buf (t+3)&3 == (t-1)&3) */                             \
    if (t_ < 29) {                                                            \
        unsigned short* stg = smem + ((t_ + 3) & 3) * BUF;                    \
        const int kn = (t_ + 3) * 32;                                         \
        gld16(gA0 + kn, stg + sA0);                                           \
        gld16(gA1 + kn, stg + sA1);                                           \
        gld16(gB0 + kn, stg + sB0);                                           \
        gld16(gB1 + kn, stg + sB1);                                           \
    }                                                                         \
    /* counted wait: own tile-(t+1) loads landed; t+2,t+3 stay in flight */   \
    if (t_ < 29)       { asm volatile("s_waitcnt vmcnt(8)" ::: "memory"); }   \
    else if (t_ == 29) { asm volatile("s_waitcnt vmcnt(4)" ::: "memory"); }   \
    else               { asm volatile("s_waitcnt vmcnt(0)" ::: "memory"); }   \
    __builtin_amdgcn_s_barrier();   /* ALL waves' tile t+1 now in LDS */      \
    /* next-tile B + A-low fragments; overlap with MFMA-B below */            \
    if (t_ < 31) {                                                            \
        const unsigned short* An = smem + ((t_ + 1) & 3) * BUF;               \
        const unsigned short* Bn = An + 8192;                                 \
        _Pragma("unroll")                                                     \
        for (int j = 0; j < 4; ++j)                                           \
            NB[j] = *(const bf16x8*)&Bn[(wn + j * 16) * 32 + loff];           \
        _Pragma("unroll")                                                     \
        for (int j = 0; j < 4; ++j)                                           \
            NA[j] = *(const bf16x8*)&An[(wm + j * 16) * 32 + loff];           \
    }                                                                         \
    /* MFMA-B: acc[4..7], zero lgkm dependency (all regs current) */          \
    __builtin_amdgcn_s_setprio(1);                                            \
    _Pragma("unroll")                                                         \
    for (int j = 0; j < 4; ++j)                                               \
        _Pragma("unroll")                                                     \
        for (int n = 0; n < 4; ++n)                                           \
            acc[4 + j][n] = __builtin_amdgcn_mfma_f32_16x16x32_bf16(          \
                CB[n], CAB[j], acc[4 + j][n], 0, 0, 0);                       \
    __builtin_amdgcn_s_setprio(0);                                            \
    /* next-tile A-high fragments; hidden under next iter's MFMA-A */         \
    if (t_ < 31) {                                                            \
        const unsigned short* An = smem + ((t_ + 1) & 3) * BUF;               \
        _Pragma("unroll")                                                     \
        for (int j = 0; j < 4; ++j)                                           \
            NAB[j] = *(const bf16x8*)&An[(wm + 64 + j * 16) * 32 + loff];     \
    }                                                                         \
  }

__global__ __launch_bounds__(512, 2) void gemm_kernel(
    const unsigned short* __restrict__ A,
    const unsigned short* __restrict__ Bp,
    const float* __restrict__ bias,
    float* __restrict__ C, int M)
{
    constexpr int K = 1024, N = 1024;
    constexpr int BUF = 16384;                    // shorts per buffer: A 8192 + B 8192
    __shared__ __align__(16) unsigned short smem[4 * BUF];   // 128 KiB

    const int tid  = threadIdx.x;
    const int lane = tid & 63;
    const int wave = tid >> 6;
    const int wm   = (wave >> 2) * 128;           // 2 M-wave-groups
    const int wn   = (wave & 3) * 64;             // 4 N-wave-groups

    // T1: XCD-aware block swizzle (nwg = 512, divisible by 8 -> bijective)
    const int nwg = gridDim.x;
    int wg = blockIdx.x;
    if ((nwg & 7) == 0) wg = (wg & 7) * (nwg >> 3) + (wg >> 3);
    const int bm = (wg >> 2) * 256;               // n fastest -> A-panel L2 reuse
    const int bn = (wg & 3) * 256;

    // ---- staging addressing (T2: linear LDS dest + pre-swizzled global src) ----
    const int qsrc = (((lane & 3) ^ ((lane >> 3) & 3))) * 8;  // element offset
    const int rA0  = (wave * 2) * 16 + (lane >> 2);
    const unsigned short* gA0 = A  + (size_t)(bm + rA0) * K + qsrc;
    const unsigned short* gA1 = A  + (size_t)(bm + rA0 + 16) * K + qsrc;
    const unsigned short* gB0 = Bp + (size_t)(bn + rA0) * K + qsrc;
    const unsigned short* gB1 = Bp + (size_t)(bn + rA0 + 16) * K + qsrc;
    const int sA0 = (wave * 2) * 512 + lane * 8;  // shorts within buf (linear)
    const int sA1 = sA0 + 512;
    const int sB0 = 8192 + sA0;
    const int sB1 = 8192 + sA1;

    // ---- fragment read offset (swizzled): 2-way bank aliasing = free ----
    const int fr   = lane & 15;
    const int quad = lane >> 4;
    const int loff = fr * 32 + ((quad ^ ((fr >> 1) & 3)) * 8);

    f32x4 acc[8][4] = {};

    // prologue: stage K-tiles 0,1,2 (12 loads/thread in flight)
#pragma unroll
    for (int kt = 0; kt < 3; ++kt) {
        unsigned short* sb = smem + kt * BUF;
        gld16(gA0 + kt * 32, sb + sA0);
        gld16(gA1 + kt * 32, sb + sA1);
        gld16(gB0 + kt * 32, sb + sB0);
        gld16(gB1 + kt * 32, sb + sB1);
    }
    asm volatile("s_waitcnt vmcnt(8)" ::: "memory");  // own tile-0 loads landed
    __builtin_amdgcn_s_barrier();                     // all waves' tile 0 in LDS

    bf16x8 afA0[4], afB0[4], bfr0[4], afA1[4], afB1[4], bfr1[4];
    {   // initial fragments: ALL of tile 0
        const unsigned short* A0 = smem;
        const unsigned short* B0 = smem + 8192;
#pragma unroll
        for (int j = 0; j < 4; ++j)
            bfr0[j] = *(const bf16x8*)&B0[(wn + j * 16) * 32 + loff];
#pragma unroll
        for (int j = 0; j < 4; ++j)
            afA0[j] = *(const bf16x8*)&A0[(wm + j * 16) * 32 + loff];
#pragma unroll
        for (int j = 0; j < 4; ++j)
            afB0[j] = *(const bf16x8*)&A0[(wm + 64 + j * 16) * 32 + loff];
    }

    for (int t = 0; t < 32; t += 2) {
        GEMM_ITER(t,     afA0, afB0, bfr0, afA1, afB1, bfr1)
        GEMM_ITER(t + 1, afA1, afB1, bfr1, afA0, afB0, bfr0)
    }

    // ---- epilogue: vectorized per-wave LDS transpose -> full 128B lines ----
    // Swapped-operand C/D layout: acc[mi][ni] reg r = C[wm+mi*16+fr][wn+ni*16+quad*4+r].
    // ds_write_b128 (2-way, free) -> ds_read_b128 (2-way) -> 256B/row stores.
    float* tb = (float*)smem + wave * 1088;   // 16 rows x 68 floats, per-wave private
    const int q4 = quad * 4;
    const float4 bvT = *(const float4*)&bias[bn + wn + fr * 4];
#pragma unroll
    for (int mi = 0; mi < 8; ++mi) {
#pragma unroll
        for (int ni = 0; ni < 4; ++ni)
            *(float4*)&tb[fr * 68 + ni * 16 + q4] = *(const float4*)&acc[mi][ni];
        // same-wave LDS: in-order pipe + compiler lgkmcnt waits; no barrier
#pragma unroll
        for (int j = 0; j < 4; ++j) {
            const int row = j * 4 + quad;
            const float4 v = *(const float4*)&tb[row * 68 + fr * 4];
            float4 o;
            o.x = v.x + bvT.x; o.y = v.y + bvT.y;
            o.z = v.z + bvT.z; o.w = v.w + bvT.w;
            *(float4*)&C[(size_t)(bm + wm + mi * 16 + row) * N + bn + wn + fr * 4] = o;
        }
    }
}

extern "C" void kernel_launch(void* const* d_in, const int* in_sizes, int n_in,
                              void* d_out, int out_size, void* d_ws, size_t ws_size,
                              hipStream_t stream)
{
    const float* x     = (const float*)d_in[0];
    const int*   cid   = (const int*)d_in[1];
    const float* gamma = (const float*)d_in[2];
    const float* beta  = (const float*)d_in[3];
    const float* scale = (const float*)d_in[4];
    const float* W     = (const float*)d_in[5];
    const float* bias  = (const float*)d_in[6];
    float* out = (float*)d_out;

    const int M = in_sizes[0] / DM;                        // 32768 tokens
    unsigned short* yb = (unsigned short*)d_ws;            // M*1024 bf16 = 64 MB
    unsigned short* Wb = yb + (size_t)M * DM;              // 1024*1024 bf16 = 2 MB

    // one wave per unit: (M + DM) units, 4 waves per 256-thread block
    ln_w_kernel<<<(M + DM) / 4, 256, 0, stream>>>(x, cid, gamma, beta, scale, W, yb, Wb, M);
    gemm_kernel<<<dim3((M / 256) * 4), 512, 0, stream>>>(yb, Wb, bias, out, M);
}